// Round 5
// baseline (71.099 us; speedup 1.0000x reference)
//
#include <hip/hip_runtime.h>
#include <hip/hip_bf16.h>

#define BB 16
#define NN 512
#define DIN 256
#define DOUT 256
#define HH 8
#define HD 32
#define EE 131072
#define MM (BB*NN)    // 8192 rows
#define BH (BB*HH)    // 128
#define DEGCAP 96

typedef unsigned short ushort_t;
typedef __attribute__((ext_vector_type(8))) short bf16x8;
typedef __attribute__((ext_vector_type(4))) float f32x4;

__device__ __forceinline__ unsigned short f2bf(float f) {
    unsigned int u = __float_as_uint(f);
    unsigned int r = (u + 0x7fffu + ((u >> 16) & 1u)) >> 16;
    return (unsigned short)r;
}

__device__ __forceinline__ void ld4bf(const ushort_t* p, float* f) {
    uint2 u = *(const uint2*)p;
    f[0] = __uint_as_float(u.x << 16);
    f[1] = __uint_as_float(u.x & 0xffff0000u);
    f[2] = __uint_as_float(u.y << 16);
    f[3] = __uint_as_float(u.y & 0xffff0000u);
}

// ---------------- fused prep: zero mask+deg | h fp32->bf16 | weight transpose ----------------
// blocks [0,136): zero 544 KB; [136,1160): h2bf; [1160,2184): wprep
__global__ __launch_bounds__(256) void prep(
    const float* __restrict__ h,
    const float* __restrict__ Wq, const float* __restrict__ Wk,
    const float* __restrict__ Wv, const float* __restrict__ Wo,
    unsigned int* __restrict__ zero_base, ushort_t* __restrict__ hb,
    ushort_t* __restrict__ Wt, ushort_t* __restrict__ Wot) {
    const int bid = blockIdx.x;
    const int t = threadIdx.x;
    if (bid < 136) {
        uint4 z = {0u, 0u, 0u, 0u};
        ((uint4*)zero_base)[bid * 256 + t] = z;   // 136*4 KB = mask(512K)+deg(32K)
    } else if (bid < 1160) {
        int chunk = (bid - 136) * 256 + t;        // 262144 chunks of 8 floats
        float4 a = *(const float4*)(h + (size_t)chunk * 8);
        float4 b = *(const float4*)(h + (size_t)chunk * 8 + 4);
        ushort_t o[8] = {f2bf(a.x), f2bf(a.y), f2bf(a.z), f2bf(a.w),
                         f2bf(b.x), f2bf(b.y), f2bf(b.z), f2bf(b.w)};
        *(uint4*)(hb + (size_t)chunk * 8) = *(const uint4*)o;
    } else {
        int tg = (bid - 1160) * 256 + t;          // 262144 = 1024 rows x 256 cols
        int n = tg >> 8, k = tg & 255;
        if (n < 768) {
            const float* W = (n < 256) ? Wq : (n < 512) ? Wk : Wv;
            Wt[(size_t)n * 256 + k] = f2bf(W[(size_t)k * 256 + (n & 255)]);
        } else {
            int nn = n - 768;
            Wot[(size_t)nn * 256 + k] = f2bf(Wo[(size_t)k * 256 + nn]);
        }
    }
}

// ---------------- mask build: row-major bitmask mask[b*512+r][16 words] ----------------
__global__ void mask_build(const int* __restrict__ src, const int* __restrict__ dst,
                           unsigned int* __restrict__ mask) {
    int t = blockIdx.x * 256 + threadIdx.x;
    if (t < EE) {
        int s = src[t], d = dst[t];
        int b = s / NN, r = s % NN, c = d % NN;
        atomicOr(&mask[((size_t)(b * NN + r)) * 16 + (c >> 5)], 1u << (c & 31));
    }
    if (t < MM) {
        atomicOr(&mask[(size_t)t * 16 + ((t & 511) >> 5)], 1u << (t & 31));
    }
}

// ---------------- CSR build from bitmask (deduped): thread = (row, word) ----------------
__global__ __launch_bounds__(256) void csr_build(
    const unsigned int* __restrict__ mask, unsigned int* __restrict__ deg,
    ushort_t* __restrict__ cols) {
    int t = blockIdx.x * 256 + threadIdx.x;   // 131072 = 8192 rows x 16 words
    int row = t >> 4, w = t & 15;
    unsigned int word = mask[(size_t)row * 16 + w];
    while (word) {
        int bit = __ffs(word) - 1;
        word &= word - 1;
        unsigned int slot = atomicAdd(&deg[row], 1u);
        if (slot < DEGCAP) cols[(size_t)row * DEGCAP + slot] = (ushort_t)(w * 32 + bit);
    }
}

// ---------------- bf16 MFMA GEMM: C[M x N] = A[M x 256] * Bt[N x 256]^T + bias ----------------
// MODE 0: N=768 fused QKV -> q/k/v all (B,H,N,HD) bf16;  MODE 1: N=256 -> fp32 out
template<int MODE>
__global__ __launch_bounds__(256) void gemm_mfma(
    const ushort_t* __restrict__ A, const ushort_t* __restrict__ Bt,
    const float* __restrict__ b0, const float* __restrict__ b1, const float* __restrict__ b2,
    ushort_t* __restrict__ qb, ushort_t* __restrict__ kb, ushort_t* __restrict__ vb,
    float* __restrict__ fout) {
    __shared__ ushort_t As[64][72];
    __shared__ ushort_t Bs[64][72];
    const int t = threadIdx.x;
    const int m0 = blockIdx.x * 64, n0 = blockIdx.y * 64;
    const int wid = t >> 6, lane = t & 63, g = lane >> 4, c = lane & 15;
    const int wr = wid >> 1, wc = wid & 1;

    f32x4 acc00 = {0.f,0.f,0.f,0.f}, acc01 = acc00, acc10 = acc00, acc11 = acc00;

    for (int k0 = 0; k0 < 256; k0 += 64) {
        #pragma unroll
        for (int i = 0; i < 2; ++i) {
            int f = t + i * 256;
            int row = f >> 3, c16 = f & 7;
            *(uint4*)&As[row][c16 * 8] = *(const uint4*)(A  + (size_t)(m0 + row) * 256 + k0 + c16 * 8);
            *(uint4*)&Bs[row][c16 * 8] = *(const uint4*)(Bt + (size_t)(n0 + row) * 256 + k0 + c16 * 8);
        }
        __syncthreads();
        #pragma unroll
        for (int kk = 0; kk < 2; ++kk) {
            bf16x8 a0 = *(const bf16x8*)&As[wr * 32 + c][kk * 32 + 8 * g];
            bf16x8 a1 = *(const bf16x8*)&As[wr * 32 + 16 + c][kk * 32 + 8 * g];
            bf16x8 bb0 = *(const bf16x8*)&Bs[wc * 32 + c][kk * 32 + 8 * g];
            bf16x8 bb1 = *(const bf16x8*)&Bs[wc * 32 + 16 + c][kk * 32 + 8 * g];
            acc00 = __builtin_amdgcn_mfma_f32_16x16x32_bf16(a0, bb0, acc00, 0, 0, 0);
            acc01 = __builtin_amdgcn_mfma_f32_16x16x32_bf16(a0, bb1, acc01, 0, 0, 0);
            acc10 = __builtin_amdgcn_mfma_f32_16x16x32_bf16(a1, bb0, acc10, 0, 0, 0);
            acc11 = __builtin_amdgcn_mfma_f32_16x16x32_bf16(a1, bb1, acc11, 0, 0, 0);
        }
        __syncthreads();
    }

    #pragma unroll
    for (int mi = 0; mi < 2; ++mi) {
        #pragma unroll
        for (int nj = 0; nj < 2; ++nj) {
            const f32x4 av = (mi == 0) ? (nj == 0 ? acc00 : acc01) : (nj == 0 ? acc10 : acc11);
            const int m_base = m0 + wr * 32 + mi * 16 + 4 * g;
            const int n_base = n0 + wc * 32 + nj * 16;
            if (MODE == 1) {
                const float bias = b0[n_base + c];
                #pragma unroll
                for (int r = 0; r < 4; ++r)
                    fout[(size_t)(m_base + r) * 256 + n_base + c] = av[r] + bias;
            } else {
                const int z = n_base >> 8, nn = n_base & 255;
                const int hh = nn >> 5, hd = (nn & 31) + c;
                const float* bp = (z == 0) ? b0 : (z == 1) ? b1 : b2;
                const float bias = bp[nn + c];
                const int b = m_base >> 9, nrow = m_base & 511;
                ushort_t* dst = (z == 0) ? qb : (z == 1) ? kb : vb;
                #pragma unroll
                for (int r = 0; r < 4; ++r)
                    dst[(((size_t)(b * 8 + hh)) * 512 + nrow + r) * 32 + hd] = f2bf(av[r] + bias);
            }
        }
    }
}

// ---------------- sparse gather attention: one wave per (b,q) row ----------------
// lane: h = lane>>3, dims (lane&7)*4 .. +3;  p = exp(s*scale - 16), out = acc/l
__global__ __launch_bounds__(256) void attn_sparse(
    const ushort_t* __restrict__ qb, const ushort_t* __restrict__ kb,
    const ushort_t* __restrict__ vb, const ushort_t* __restrict__ cols,
    const unsigned int* __restrict__ deg, ushort_t* __restrict__ attnb) {
    const int wid = threadIdx.x >> 6, lane = threadIdx.x & 63;
    const int row = blockIdx.x * 4 + wid;     // 0..8191
    const int b = row >> 9, q = row & 511;
    const int h = lane >> 3, d4 = (lane & 7) * 4;
    const float SCALE = 0.17677669529663687f;  // 1/sqrt(32)

    const ushort_t* hslab_k = kb + ((size_t)(b * 8 + h) * 512) * 32 + d4;
    const ushort_t* hslab_v = vb + ((size_t)(b * 8 + h) * 512) * 32 + d4;
    float qf[4];
    ld4bf(qb + (((size_t)(b * 8 + h) * 512) + q) * 32 + d4, qf);

    int dg = (int)deg[row];
    dg = dg < DEGCAP ? dg : DEGCAP;
    const ushort_t* cl = cols + (size_t)row * DEGCAP;

    float acc[4] = {0.f, 0.f, 0.f, 0.f};
    float l = 0.f;
    #pragma unroll 2
    for (int e = 0; e < dg; ++e) {
        int col = cl[e];
        float kf[4], vf[4];
        ld4bf(hslab_k + (size_t)col * 32, kf);
        ld4bf(hslab_v + (size_t)col * 32, vf);
        float s = qf[0] * kf[0];
        s = fmaf(qf[1], kf[1], s);
        s = fmaf(qf[2], kf[2], s);
        s = fmaf(qf[3], kf[3], s);
        s += __shfl_xor(s, 1);
        s += __shfl_xor(s, 2);
        s += __shfl_xor(s, 4);
        float p = __expf(fmaf(s, SCALE, -16.0f));
        l += p;
        acc[0] = fmaf(p, vf[0], acc[0]);
        acc[1] = fmaf(p, vf[1], acc[1]);
        acc[2] = fmaf(p, vf[2], acc[2]);
        acc[3] = fmaf(p, vf[3], acc[3]);
    }
    float rl = 1.0f / l;
    ushort_t o[4] = {f2bf(acc[0] * rl), f2bf(acc[1] * rl), f2bf(acc[2] * rl), f2bf(acc[3] * rl)};
    *(uint2*)(attnb + (size_t)row * 256 + lane * 4) = *(const uint2*)o;
}

extern "C" void kernel_launch(void* const* d_in, const int* in_sizes, int n_in,
                              void* d_out, int out_size, void* d_ws, size_t ws_size,
                              hipStream_t stream) {
    const float* hin = (const float*)d_in[0];
    const int* src   = (const int*)d_in[1];
    const int* dst   = (const int*)d_in[2];
    const float* Wq  = (const float*)d_in[3];
    const float* bq  = (const float*)d_in[4];
    const float* Wk  = (const float*)d_in[5];
    const float* bk  = (const float*)d_in[6];
    const float* Wv  = (const float*)d_in[7];
    const float* bv  = (const float*)d_in[8];
    const float* Wo  = (const float*)d_in[9];
    const float* bo  = (const float*)d_in[10];

    char* ws = (char*)d_ws;
    unsigned int* mask = (unsigned int*)ws;                      // 512 KB
    unsigned int* deg  = (unsigned int*)(ws + 524288);           // 32 KB (zeroed with mask)
    ushort_t* cols  = (ushort_t*)(ws + 557056);                  // 1.5 MB
    ushort_t* hb    = (ushort_t*)(ws + 2129920);                 // 4 MB
    ushort_t* qb    = (ushort_t*)(ws + 6324224);                 // 4 MB
    ushort_t* kb    = (ushort_t*)(ws + 10518528);                // 4 MB
    ushort_t* vb    = (ushort_t*)(ws + 14712832);                // 4 MB
    ushort_t* attnb = (ushort_t*)(ws + 18907136);                // 4 MB
    ushort_t* Wt    = (ushort_t*)(ws + 23101440);                // 384 KB
    ushort_t* Wot   = (ushort_t*)(ws + 23494656);                // 128 KB
    float* out = (float*)d_out;

    prep<<<2184, 256, 0, stream>>>(hin, Wq, Wk, Wv, Wo, mask, hb, Wt, Wot);
    mask_build<<<(EE + 255) / 256, 256, 0, stream>>>(src, dst, mask);
    csr_build<<<512, 256, 0, stream>>>(mask, deg, cols);
    gemm_mfma<0><<<dim3(MM / 64, 768 / 64), 256, 0, stream>>>(hb, Wt, bq, bk, bv,
                                                              qb, kb, vb, nullptr);
    attn_sparse<<<MM / 4, 256, 0, stream>>>(qb, kb, vb, cols, deg, attnb);
    gemm_mfma<1><<<dim3(MM / 64, 256 / 64), 256, 0, stream>>>(attnb, Wot, bo, nullptr, nullptr,
                                                              nullptr, nullptr, nullptr, out);
}

// Round 6
// 55.829 us; speedup vs baseline: 1.2735x; 1.2735x over previous
//
#include <hip/hip_runtime.h>
#include <hip/hip_bf16.h>

#define BB 16
#define NN 512
#define DIN 256
#define DOUT 256
#define HH 8
#define HD 32
#define EE 131072
#define MM (BB*NN)    // 8192 rows
#define BH (BB*HH)    // 128

typedef unsigned short ushort_t;
typedef __attribute__((ext_vector_type(8))) short bf16x8;
typedef __attribute__((ext_vector_type(4))) float f32x4;

__device__ __forceinline__ unsigned short f2bf(float f) {
    unsigned int u = __float_as_uint(f);
    unsigned int r = (u + 0x7fffu + ((u >> 16) & 1u)) >> 16;
    return (unsigned short)r;
}

// unpack 16 bf16 (32B) -> 16 fp32
__device__ __forceinline__ void ld16bf(const ushort_t* p, float* f) {
    uint4 u0 = *(const uint4*)p;
    uint4 u1 = *(const uint4*)(p + 8);
    unsigned int w[8] = {u0.x, u0.y, u0.z, u0.w, u1.x, u1.y, u1.z, u1.w};
    #pragma unroll
    for (int i = 0; i < 8; ++i) {
        f[2 * i]     = __uint_as_float(w[i] << 16);
        f[2 * i + 1] = __uint_as_float(w[i] & 0xffff0000u);
    }
}

// ---------------- fused prep: zero mask | h fp32->bf16 | weight transpose ----------------
// blocks [0,128): zero 512 KB; [128,1152): h2bf; [1152,2176): wprep
__global__ __launch_bounds__(256) void prep(
    const float* __restrict__ h,
    const float* __restrict__ Wq, const float* __restrict__ Wk,
    const float* __restrict__ Wv, const float* __restrict__ Wo,
    unsigned int* __restrict__ mask, ushort_t* __restrict__ hb,
    ushort_t* __restrict__ Wt, ushort_t* __restrict__ Wot) {
    const int bid = blockIdx.x;
    const int t = threadIdx.x;
    if (bid < 128) {
        uint4 z = {0u, 0u, 0u, 0u};
        ((uint4*)mask)[bid * 256 + t] = z;        // 512 KB
    } else if (bid < 1152) {
        int chunk = (bid - 128) * 256 + t;        // 262144 chunks of 8 floats
        float4 a = *(const float4*)(h + (size_t)chunk * 8);
        float4 b = *(const float4*)(h + (size_t)chunk * 8 + 4);
        ushort_t o[8] = {f2bf(a.x), f2bf(a.y), f2bf(a.z), f2bf(a.w),
                         f2bf(b.x), f2bf(b.y), f2bf(b.z), f2bf(b.w)};
        *(uint4*)(hb + (size_t)chunk * 8) = *(const uint4*)o;
    } else {
        int tg = (bid - 1152) * 256 + t;          // 262144 = 1024 rows x 256 cols
        int n = tg >> 8, k = tg & 255;
        if (n < 768) {
            const float* W = (n < 256) ? Wq : (n < 512) ? Wk : Wv;
            Wt[(size_t)n * 256 + k] = f2bf(W[(size_t)k * 256 + (n & 255)]);
        } else {
            int nn = n - 768;
            Wot[(size_t)nn * 256 + k] = f2bf(Wo[(size_t)k * 256 + nn]);
        }
    }
}

// ---------------- mask build: row-major bitmask mask[b*512+r][16 words] ----------------
__global__ void mask_build(const int* __restrict__ src, const int* __restrict__ dst,
                           unsigned int* __restrict__ mask) {
    int t = blockIdx.x * 256 + threadIdx.x;
    if (t < EE) {
        int s = src[t], d = dst[t];
        int b = s / NN, r = s % NN, c = d % NN;
        atomicOr(&mask[((size_t)(b * NN + r)) * 16 + (c >> 5)], 1u << (c & 31));
    }
    if (t < MM) {
        atomicOr(&mask[(size_t)t * 16 + ((t & 511) >> 5)], 1u << (t & 31));
    }
}

// ---------------- bf16 MFMA GEMM (unchanged, validated) ----------------
template<int MODE>
__global__ __launch_bounds__(256) void gemm_mfma(
    const ushort_t* __restrict__ A, const ushort_t* __restrict__ Bt,
    const float* __restrict__ b0, const float* __restrict__ b1, const float* __restrict__ b2,
    ushort_t* __restrict__ qb, ushort_t* __restrict__ kb, ushort_t* __restrict__ vb,
    float* __restrict__ fout) {
    __shared__ ushort_t As[64][72];
    __shared__ ushort_t Bs[64][72];
    const int t = threadIdx.x;
    const int m0 = blockIdx.x * 64, n0 = blockIdx.y * 64;
    const int wid = t >> 6, lane = t & 63, g = lane >> 4, c = lane & 15;
    const int wr = wid >> 1, wc = wid & 1;

    f32x4 acc00 = {0.f,0.f,0.f,0.f}, acc01 = acc00, acc10 = acc00, acc11 = acc00;

    for (int k0 = 0; k0 < 256; k0 += 64) {
        #pragma unroll
        for (int i = 0; i < 2; ++i) {
            int f = t + i * 256;
            int row = f >> 3, c16 = f & 7;
            *(uint4*)&As[row][c16 * 8] = *(const uint4*)(A  + (size_t)(m0 + row) * 256 + k0 + c16 * 8);
            *(uint4*)&Bs[row][c16 * 8] = *(const uint4*)(Bt + (size_t)(n0 + row) * 256 + k0 + c16 * 8);
        }
        __syncthreads();
        #pragma unroll
        for (int kk = 0; kk < 2; ++kk) {
            bf16x8 a0 = *(const bf16x8*)&As[wr * 32 + c][kk * 32 + 8 * g];
            bf16x8 a1 = *(const bf16x8*)&As[wr * 32 + 16 + c][kk * 32 + 8 * g];
            bf16x8 bb0 = *(const bf16x8*)&Bs[wc * 32 + c][kk * 32 + 8 * g];
            bf16x8 bb1 = *(const bf16x8*)&Bs[wc * 32 + 16 + c][kk * 32 + 8 * g];
            acc00 = __builtin_amdgcn_mfma_f32_16x16x32_bf16(a0, bb0, acc00, 0, 0, 0);
            acc01 = __builtin_amdgcn_mfma_f32_16x16x32_bf16(a0, bb1, acc01, 0, 0, 0);
            acc10 = __builtin_amdgcn_mfma_f32_16x16x32_bf16(a1, bb0, acc10, 0, 0, 0);
            acc11 = __builtin_amdgcn_mfma_f32_16x16x32_bf16(a1, bb1, acc11, 0, 0, 0);
        }
        __syncthreads();
    }

    #pragma unroll
    for (int mi = 0; mi < 2; ++mi) {
        #pragma unroll
        for (int nj = 0; nj < 2; ++nj) {
            const f32x4 av = (mi == 0) ? (nj == 0 ? acc00 : acc01) : (nj == 0 ? acc10 : acc11);
            const int m_base = m0 + wr * 32 + mi * 16 + 4 * g;
            const int n_base = n0 + wc * 32 + nj * 16;
            if (MODE == 1) {
                const float bias = b0[n_base + c];
                #pragma unroll
                for (int r = 0; r < 4; ++r)
                    fout[(size_t)(m_base + r) * 256 + n_base + c] = av[r] + bias;
            } else {
                const int z = n_base >> 8, nn = n_base & 255;
                const int hh = nn >> 5, hd = (nn & 31) + c;
                const float* bp = (z == 0) ? b0 : (z == 1) ? b1 : b2;
                const float bias = bp[nn + c];
                const int b = m_base >> 9, nrow = m_base & 511;
                ushort_t* dst = (z == 0) ? qb : (z == 1) ? kb : vb;
                #pragma unroll
                for (int r = 0; r < 4; ++r)
                    dst[(((size_t)(b * 8 + hh)) * 512 + nrow + r) * 32 + hd] = f2bf(av[r] + bias);
            }
        }
    }
}

// ---------------- sparse attention v2: one wave per (b,q) row ----------------
// lane = (e2 = lane>>4, h = (lane>>1)&7, half = lane&1): 4 edge slots x 8 heads x 16 dims
__global__ __launch_bounds__(256) void attn_sparse2(
    const ushort_t* __restrict__ qb, const ushort_t* __restrict__ kb,
    const ushort_t* __restrict__ vb, const unsigned int* __restrict__ mask,
    ushort_t* __restrict__ attnb) {
    __shared__ ushort_t colsS[4][64];
    const int wid = threadIdx.x >> 6, lane = threadIdx.x & 63;
    const int row = blockIdx.x * 4 + wid;     // 0..8191
    const int b = row >> 9, q = row & 511;
    const int e2 = lane >> 4, h = (lane >> 1) & 7, half = lane & 1;
    const float SCALE = 0.17677669529663687f;  // 1/sqrt(32)

    // ---- extract set bits of mask row into per-wave LDS col list (deduped by bitmask) ----
    unsigned int word = (lane < 16) ? mask[(size_t)row * 16 + lane] : 0u;
    int pc = __popc(word);
    int pre = pc;
    #pragma unroll
    for (int o = 1; o < 16; o <<= 1) {
        int v = __shfl_up(pre, o);
        if ((lane & 15) >= o) pre += v;
    }
    int off = pre - pc;
    while (word) {
        int bit = __ffs(word) - 1;
        word &= word - 1;
        if (off < 64) colsS[wid][off] = (ushort_t)(lane * 32 + bit);
        ++off;
    }
    int cnt = __shfl(pre, 15);
    cnt = cnt < 64 ? cnt : 64;

    const size_t hb_base = ((size_t)(b * 8 + h)) * 512;   // row base of this head's slab
    const int d0 = half * 16;
    float qf[16];
    ld16bf(qb + (hb_base + q) * 32 + d0, qf);

    float acc[16];
    #pragma unroll
    for (int d = 0; d < 16; ++d) acc[d] = 0.f;
    float l = 0.f;

    #pragma unroll 2
    for (int e = 0; e < cnt; e += 4) {
        int slot = e + e2;
        int col = colsS[wid][slot < cnt ? slot : 0];
        const ushort_t* kp = kb + (hb_base + col) * 32 + d0;
        const ushort_t* vp = vb + (hb_base + col) * 32 + d0;
        float kf[16], vf[16];
        ld16bf(kp, kf);
        ld16bf(vp, vf);
        float s0 = 0.f, s1 = 0.f;
        #pragma unroll
        for (int d = 0; d < 8; ++d) {
            s0 = fmaf(qf[d], kf[d], s0);
            s1 = fmaf(qf[8 + d], kf[8 + d], s1);
        }
        float s = s0 + s1;
        s += __shfl_xor(s, 1);                 // combine the two 16-dim halves
        float p = (slot < cnt) ? __expf(fmaf(s, SCALE, -16.0f)) : 0.f;
        l += p;
        #pragma unroll
        for (int d = 0; d < 16; ++d) acc[d] = fmaf(p, vf[d], acc[d]);
    }

    // reduce across the 4 edge slots (lane bits 4,5)
    #pragma unroll
    for (int d = 0; d < 16; ++d) {
        acc[d] += __shfl_xor(acc[d], 16);
        acc[d] += __shfl_xor(acc[d], 32);
    }
    l += __shfl_xor(l, 16);
    l += __shfl_xor(l, 32);

    if (e2 == 0) {
        float rl = 1.0f / l;
        ushort_t o[16];
        #pragma unroll
        for (int d = 0; d < 16; ++d) o[d] = f2bf(acc[d] * rl);
        ushort_t* op = attnb + (size_t)row * 256 + h * 32 + d0;
        *(uint4*)op       = *(const uint4*)o;
        *(uint4*)(op + 8) = *(const uint4*)(o + 8);
    }
}

extern "C" void kernel_launch(void* const* d_in, const int* in_sizes, int n_in,
                              void* d_out, int out_size, void* d_ws, size_t ws_size,
                              hipStream_t stream) {
    const float* hin = (const float*)d_in[0];
    const int* src   = (const int*)d_in[1];
    const int* dst   = (const int*)d_in[2];
    const float* Wq  = (const float*)d_in[3];
    const float* bq  = (const float*)d_in[4];
    const float* Wk  = (const float*)d_in[5];
    const float* bk  = (const float*)d_in[6];
    const float* Wv  = (const float*)d_in[7];
    const float* bv  = (const float*)d_in[8];
    const float* Wo  = (const float*)d_in[9];
    const float* bo  = (const float*)d_in[10];

    char* ws = (char*)d_ws;
    unsigned int* mask = (unsigned int*)ws;                      // 512 KB
    ushort_t* hb    = (ushort_t*)(ws + 2129920);                 // 4 MB
    ushort_t* qb    = (ushort_t*)(ws + 6324224);                 // 4 MB
    ushort_t* kb    = (ushort_t*)(ws + 10518528);                // 4 MB
    ushort_t* vb    = (ushort_t*)(ws + 14712832);                // 4 MB
    ushort_t* attnb = (ushort_t*)(ws + 18907136);                // 4 MB
    ushort_t* Wt    = (ushort_t*)(ws + 23101440);                // 384 KB
    ushort_t* Wot   = (ushort_t*)(ws + 23494656);                // 128 KB
    float* out = (float*)d_out;

    prep<<<2176, 256, 0, stream>>>(hin, Wq, Wk, Wv, Wo, mask, hb, Wt, Wot);
    mask_build<<<(EE + 255) / 256, 256, 0, stream>>>(src, dst, mask);
    gemm_mfma<0><<<dim3(MM / 64, 768 / 64), 256, 0, stream>>>(hb, Wt, bq, bk, bv,
                                                              qb, kb, vb, nullptr);
    attn_sparse2<<<MM / 4, 256, 0, stream>>>(qb, kb, vb, mask, attnb);
    gemm_mfma<1><<<dim3(MM / 64, 256 / 64), 256, 0, stream>>>(attnb, Wot, bo, nullptr, nullptr,
                                                              nullptr, nullptr, nullptr, out);
}

// Round 7
// 51.181 us; speedup vs baseline: 1.3892x; 1.0908x over previous
//
#include <hip/hip_runtime.h>
#include <hip/hip_bf16.h>

#define BB 16
#define NN 512
#define DIN 256
#define DOUT 256
#define HH 8
#define HD 32
#define EE 131072
#define MM (BB*NN)    // 8192 rows
#define BH (BB*HH)    // 128

typedef unsigned short ushort_t;
typedef __attribute__((ext_vector_type(8))) short bf16x8;
typedef __attribute__((ext_vector_type(4))) float f32x4;

__device__ __forceinline__ unsigned short f2bf(float f) {
    unsigned int u = __float_as_uint(f);
    unsigned int r = (u + 0x7fffu + ((u >> 16) & 1u)) >> 16;
    return (unsigned short)r;
}

// unpack 16 bf16 (32B) -> 16 fp32
__device__ __forceinline__ void ld16bf(const ushort_t* p, float* f) {
    uint4 u0 = *(const uint4*)p;
    uint4 u1 = *(const uint4*)(p + 8);
    unsigned int w[8] = {u0.x, u0.y, u0.z, u0.w, u1.x, u1.y, u1.z, u1.w};
    #pragma unroll
    for (int i = 0; i < 8; ++i) {
        f[2 * i]     = __uint_as_float(w[i] << 16);
        f[2 * i + 1] = __uint_as_float(w[i] & 0xffff0000u);
    }
}

// ---------------- fused prep: zero mask | h fp32->bf16 | weight transpose ----------------
__global__ __launch_bounds__(256) void prep(
    const float* __restrict__ h,
    const float* __restrict__ Wq, const float* __restrict__ Wk,
    const float* __restrict__ Wv, const float* __restrict__ Wo,
    unsigned int* __restrict__ mask, ushort_t* __restrict__ hb,
    ushort_t* __restrict__ Wt, ushort_t* __restrict__ Wot) {
    const int bid = blockIdx.x;
    const int t = threadIdx.x;
    if (bid < 128) {
        uint4 z = {0u, 0u, 0u, 0u};
        ((uint4*)mask)[bid * 256 + t] = z;        // 512 KB
    } else if (bid < 1152) {
        int chunk = (bid - 128) * 256 + t;        // 262144 chunks of 8 floats
        float4 a = *(const float4*)(h + (size_t)chunk * 8);
        float4 b = *(const float4*)(h + (size_t)chunk * 8 + 4);
        ushort_t o[8] = {f2bf(a.x), f2bf(a.y), f2bf(a.z), f2bf(a.w),
                         f2bf(b.x), f2bf(b.y), f2bf(b.z), f2bf(b.w)};
        *(uint4*)(hb + (size_t)chunk * 8) = *(const uint4*)o;
    } else {
        int tg = (bid - 1152) * 256 + t;          // 262144 = 1024 rows x 256 cols
        int n = tg >> 8, k = tg & 255;
        if (n < 768) {
            const float* W = (n < 256) ? Wq : (n < 512) ? Wk : Wv;
            Wt[(size_t)n * 256 + k] = f2bf(W[(size_t)k * 256 + (n & 255)]);
        } else {
            int nn = n - 768;
            Wot[(size_t)nn * 256 + k] = f2bf(Wo[(size_t)k * 256 + nn]);
        }
    }
}

// ---------------- mask build: row-major bitmask mask[b*512+r][16 words] ----------------
__global__ void mask_build(const int* __restrict__ src, const int* __restrict__ dst,
                           unsigned int* __restrict__ mask) {
    int t = blockIdx.x * 256 + threadIdx.x;
    if (t < EE) {
        int s = src[t], d = dst[t];
        int b = s / NN, r = s % NN, c = d % NN;
        atomicOr(&mask[((size_t)(b * NN + r)) * 16 + (c >> 5)], 1u << (c & 31));
    }
    if (t < MM) {
        atomicOr(&mask[(size_t)t * 16 + ((t & 511) >> 5)], 1u << (t & 31));
    }
}

// ---------------- 128x128 bf16 MFMA GEMM for QKV: C = A[M x 256] * Bt[768 x 256]^T ----------------
// 4 waves (2x2), per-wave 64x64 (4x4 frags). Scatter to q/k/v (B,H,N,HD) bf16.
__global__ __launch_bounds__(256) void gemm_qkv(
    const ushort_t* __restrict__ A, const ushort_t* __restrict__ Bt,
    const float* __restrict__ b0, const float* __restrict__ b1, const float* __restrict__ b2,
    ushort_t* __restrict__ qb, ushort_t* __restrict__ kb, ushort_t* __restrict__ vb) {
    __shared__ ushort_t As[128][68];   // 136B stride -> ~4-way max on b128 frag reads
    __shared__ ushort_t Bs[128][68];
    const int t = threadIdx.x;
    const int m0 = blockIdx.x * 128, n0 = blockIdx.y * 128;
    const int wid = t >> 6, lane = t & 63, g = lane >> 4, c = lane & 15;
    const int wr = wid >> 1, wc = wid & 1;

    f32x4 acc[4][4];
    #pragma unroll
    for (int mi = 0; mi < 4; ++mi)
        #pragma unroll
        for (int nj = 0; nj < 4; ++nj) acc[mi][nj] = (f32x4){0.f, 0.f, 0.f, 0.f};

    for (int k0 = 0; k0 < 256; k0 += 64) {
        #pragma unroll
        for (int i = 0; i < 4; ++i) {
            int f = t + i * 256;               // 1024 chunks of 8 bf16
            int row = f >> 3, c16 = f & 7;
            *(uint4*)&As[row][c16 * 8] = *(const uint4*)(A  + (size_t)(m0 + row) * 256 + k0 + c16 * 8);
            *(uint4*)&Bs[row][c16 * 8] = *(const uint4*)(Bt + (size_t)(n0 + row) * 256 + k0 + c16 * 8);
        }
        __syncthreads();
        #pragma unroll
        for (int kk = 0; kk < 2; ++kk) {
            bf16x8 av[4], bv4[4];
            #pragma unroll
            for (int mi = 0; mi < 4; ++mi) av[mi]  = *(const bf16x8*)&As[wr * 64 + mi * 16 + c][kk * 32 + 8 * g];
            #pragma unroll
            for (int nj = 0; nj < 4; ++nj) bv4[nj] = *(const bf16x8*)&Bs[wc * 64 + nj * 16 + c][kk * 32 + 8 * g];
            #pragma unroll
            for (int mi = 0; mi < 4; ++mi)
                #pragma unroll
                for (int nj = 0; nj < 4; ++nj)
                    acc[mi][nj] = __builtin_amdgcn_mfma_f32_16x16x32_bf16(av[mi], bv4[nj], acc[mi][nj], 0, 0, 0);
        }
        __syncthreads();
    }

    #pragma unroll
    for (int mi = 0; mi < 4; ++mi) {
        #pragma unroll
        for (int nj = 0; nj < 4; ++nj) {
            const f32x4 av = acc[mi][nj];
            const int m_base = m0 + wr * 64 + mi * 16 + 4 * g;
            const int n_base = n0 + wc * 64 + nj * 16;
            const int z = n_base >> 8, nn = n_base & 255;
            const int hh = nn >> 5, hd = (nn & 31) + c;
            const float* bp = (z == 0) ? b0 : (z == 1) ? b1 : b2;
            const float bias = bp[nn + c];
            const int b = m_base >> 9, nrow = m_base & 511;
            ushort_t* dst = (z == 0) ? qb : (z == 1) ? kb : vb;
            #pragma unroll
            for (int r = 0; r < 4; ++r)
                dst[(((size_t)(b * 8 + hh)) * 512 + nrow + r) * 32 + hd] = f2bf(av[r] + bias);
        }
    }
}

// ---------------- 64x64 bf16 MFMA GEMM for out-proj (validated) ----------------
__global__ __launch_bounds__(256) void gemm_out(
    const ushort_t* __restrict__ A, const ushort_t* __restrict__ Bt,
    const float* __restrict__ b0, float* __restrict__ fout) {
    __shared__ ushort_t As[64][72];
    __shared__ ushort_t Bs[64][72];
    const int t = threadIdx.x;
    const int m0 = blockIdx.x * 64, n0 = blockIdx.y * 64;
    const int wid = t >> 6, lane = t & 63, g = lane >> 4, c = lane & 15;
    const int wr = wid >> 1, wc = wid & 1;

    f32x4 acc00 = {0.f,0.f,0.f,0.f}, acc01 = acc00, acc10 = acc00, acc11 = acc00;

    for (int k0 = 0; k0 < 256; k0 += 64) {
        #pragma unroll
        for (int i = 0; i < 2; ++i) {
            int f = t + i * 256;
            int row = f >> 3, c16 = f & 7;
            *(uint4*)&As[row][c16 * 8] = *(const uint4*)(A  + (size_t)(m0 + row) * 256 + k0 + c16 * 8);
            *(uint4*)&Bs[row][c16 * 8] = *(const uint4*)(Bt + (size_t)(n0 + row) * 256 + k0 + c16 * 8);
        }
        __syncthreads();
        #pragma unroll
        for (int kk = 0; kk < 2; ++kk) {
            bf16x8 a0 = *(const bf16x8*)&As[wr * 32 + c][kk * 32 + 8 * g];
            bf16x8 a1 = *(const bf16x8*)&As[wr * 32 + 16 + c][kk * 32 + 8 * g];
            bf16x8 bb0 = *(const bf16x8*)&Bs[wc * 32 + c][kk * 32 + 8 * g];
            bf16x8 bb1 = *(const bf16x8*)&Bs[wc * 32 + 16 + c][kk * 32 + 8 * g];
            acc00 = __builtin_amdgcn_mfma_f32_16x16x32_bf16(a0, bb0, acc00, 0, 0, 0);
            acc01 = __builtin_amdgcn_mfma_f32_16x16x32_bf16(a0, bb1, acc01, 0, 0, 0);
            acc10 = __builtin_amdgcn_mfma_f32_16x16x32_bf16(a1, bb0, acc10, 0, 0, 0);
            acc11 = __builtin_amdgcn_mfma_f32_16x16x32_bf16(a1, bb1, acc11, 0, 0, 0);
        }
        __syncthreads();
    }

    #pragma unroll
    for (int mi = 0; mi < 2; ++mi) {
        #pragma unroll
        for (int nj = 0; nj < 2; ++nj) {
            const f32x4 av = (mi == 0) ? (nj == 0 ? acc00 : acc01) : (nj == 0 ? acc10 : acc11);
            const int m_base = m0 + wr * 32 + mi * 16 + 4 * g;
            const int n_base = n0 + wc * 32 + nj * 16;
            const float bias = b0[n_base + c];
            #pragma unroll
            for (int r = 0; r < 4; ++r)
                fout[(size_t)(m_base + r) * 256 + n_base + c] = av[r] + bias;
        }
    }
}

// ---------------- sparse attention v3: XCD-graph-locality swizzle ----------------
// XCD x (blockIdx&7 under round-robin) handles graphs {2x, 2x+1}: per-XCD K+V set = 1 MB (L2-fit)
__global__ __launch_bounds__(256) void attn_sparse3(
    const ushort_t* __restrict__ qb, const ushort_t* __restrict__ kb,
    const ushort_t* __restrict__ vb, const unsigned int* __restrict__ mask,
    ushort_t* __restrict__ attnb) {
    __shared__ ushort_t colsS[4][64];
    const int wid = threadIdx.x >> 6, lane = threadIdx.x & 63;
    const int xcd = blockIdx.x & 7, j = blockIdx.x >> 3;        // 2048 blocks
    const int b = xcd * 2 + (j >> 7);                           // graph
    const int q = (j & 127) * 4 + wid;
    const int row = b * 512 + q;
    const int e2 = lane >> 4, h = (lane >> 1) & 7, half = lane & 1;
    const float SCALE = 0.17677669529663687f;  // 1/sqrt(32)

    // extract set bits of mask row into per-wave LDS col list (deduped by bitmask)
    unsigned int word = (lane < 16) ? mask[(size_t)row * 16 + lane] : 0u;
    int pc = __popc(word);
    int pre = pc;
    #pragma unroll
    for (int o = 1; o < 16; o <<= 1) {
        int v = __shfl_up(pre, o);
        if ((lane & 15) >= o) pre += v;
    }
    int off = pre - pc;
    while (word) {
        int bit = __ffs(word) - 1;
        word &= word - 1;
        if (off < 64) colsS[wid][off] = (ushort_t)(lane * 32 + bit);
        ++off;
    }
    int cnt = __shfl(pre, 15);
    cnt = cnt < 64 ? cnt : 64;

    const size_t hb_base = ((size_t)(b * 8 + h)) * 512;
    const int d0 = half * 16;
    float qf[16];
    ld16bf(qb + (hb_base + q) * 32 + d0, qf);

    float acc[16];
    #pragma unroll
    for (int d = 0; d < 16; ++d) acc[d] = 0.f;
    float l = 0.f;

    #pragma unroll 2
    for (int e = 0; e < cnt; e += 4) {
        int slot = e + e2;
        int col = colsS[wid][slot < cnt ? slot : 0];
        const ushort_t* kp = kb + (hb_base + col) * 32 + d0;
        const ushort_t* vp = vb + (hb_base + col) * 32 + d0;
        float kf[16], vf[16];
        ld16bf(kp, kf);
        ld16bf(vp, vf);
        float s0 = 0.f, s1 = 0.f;
        #pragma unroll
        for (int d = 0; d < 8; ++d) {
            s0 = fmaf(qf[d], kf[d], s0);
            s1 = fmaf(qf[8 + d], kf[8 + d], s1);
        }
        float s = s0 + s1;
        s += __shfl_xor(s, 1);
        float p = (slot < cnt) ? __expf(fmaf(s, SCALE, -16.0f)) : 0.f;
        l += p;
        #pragma unroll
        for (int d = 0; d < 16; ++d) acc[d] = fmaf(p, vf[d], acc[d]);
    }

    #pragma unroll
    for (int d = 0; d < 16; ++d) {
        acc[d] += __shfl_xor(acc[d], 16);
        acc[d] += __shfl_xor(acc[d], 32);
    }
    l += __shfl_xor(l, 16);
    l += __shfl_xor(l, 32);

    if (e2 == 0) {
        float rl = 1.0f / l;
        ushort_t o[16];
        #pragma unroll
        for (int d = 0; d < 16; ++d) o[d] = f2bf(acc[d] * rl);
        ushort_t* op = attnb + (size_t)row * 256 + h * 32 + d0;
        *(uint4*)op       = *(const uint4*)o;
        *(uint4*)(op + 8) = *(const uint4*)(o + 8);
    }
}

extern "C" void kernel_launch(void* const* d_in, const int* in_sizes, int n_in,
                              void* d_out, int out_size, void* d_ws, size_t ws_size,
                              hipStream_t stream) {
    const float* hin = (const float*)d_in[0];
    const int* src   = (const int*)d_in[1];
    const int* dst   = (const int*)d_in[2];
    const float* Wq  = (const float*)d_in[3];
    const float* bq  = (const float*)d_in[4];
    const float* Wk  = (const float*)d_in[5];
    const float* bk  = (const float*)d_in[6];
    const float* Wv  = (const float*)d_in[7];
    const float* bv  = (const float*)d_in[8];
    const float* Wo  = (const float*)d_in[9];
    const float* bo  = (const float*)d_in[10];

    char* ws = (char*)d_ws;
    unsigned int* mask = (unsigned int*)ws;                      // 512 KB
    ushort_t* hb    = (ushort_t*)(ws + 2129920);                 // 4 MB
    ushort_t* qb    = (ushort_t*)(ws + 6324224);                 // 4 MB
    ushort_t* kb    = (ushort_t*)(ws + 10518528);                // 4 MB
    ushort_t* vb    = (ushort_t*)(ws + 14712832);                // 4 MB
    ushort_t* attnb = (ushort_t*)(ws + 18907136);                // 4 MB
    ushort_t* Wt    = (ushort_t*)(ws + 23101440);                // 384 KB
    ushort_t* Wot   = (ushort_t*)(ws + 23494656);                // 128 KB
    float* out = (float*)d_out;

    prep<<<2176, 256, 0, stream>>>(hin, Wq, Wk, Wv, Wo, mask, hb, Wt, Wot);
    mask_build<<<(EE + 255) / 256, 256, 0, stream>>>(src, dst, mask);
    gemm_qkv<<<dim3(MM / 128, 768 / 128), 256, 0, stream>>>(hb, Wt, bq, bk, bv, qb, kb, vb);
    attn_sparse3<<<MM / 4, 256, 0, stream>>>(qb, kb, vb, mask, attnb);
    gemm_out<<<dim3(MM / 64, 256 / 64), 256, 0, stream>>>(attnb, Wot, bo, out);
}

// Round 8
// 48.566 us; speedup vs baseline: 1.4640x; 1.0539x over previous
//
#include <hip/hip_runtime.h>
#include <hip/hip_bf16.h>

#define BB 16
#define NN 512
#define DIN 256
#define DOUT 256
#define HH 8
#define HD 32
#define EE 131072
#define MM (BB*NN)    // 8192 rows
#define BH (BB*HH)    // 128

typedef unsigned short ushort_t;
typedef __attribute__((ext_vector_type(8))) short bf16x8;
typedef __attribute__((ext_vector_type(4))) float f32x4;

__device__ __forceinline__ unsigned short f2bf(float f) {
    unsigned int u = __float_as_uint(f);
    unsigned int r = (u + 0x7fffu + ((u >> 16) & 1u)) >> 16;
    return (unsigned short)r;
}

// async global->LDS, 16B per lane; dest = wave-uniform base + lane*16 (HW rule)
__device__ __forceinline__ void gload16(const ushort_t* g, ushort_t* l) {
    __builtin_amdgcn_global_load_lds((__attribute__((address_space(1))) void*)(void*)g,
                                     (__attribute__((address_space(3))) void*)l, 16, 0, 0);
}

// unpack 16 bf16 (32B) -> 16 fp32
__device__ __forceinline__ void ld16bf(const ushort_t* p, float* f) {
    uint4 u0 = *(const uint4*)p;
    uint4 u1 = *(const uint4*)(p + 8);
    unsigned int w[8] = {u0.x, u0.y, u0.z, u0.w, u1.x, u1.y, u1.z, u1.w};
    #pragma unroll
    for (int i = 0; i < 8; ++i) {
        f[2 * i]     = __uint_as_float(w[i] << 16);
        f[2 * i + 1] = __uint_as_float(w[i] & 0xffff0000u);
    }
}

// ---------------- fused prep: zero mask | h fp32->bf16 | weight transpose ----------------
__global__ __launch_bounds__(256) void prep(
    const float* __restrict__ h,
    const float* __restrict__ Wq, const float* __restrict__ Wk,
    const float* __restrict__ Wv, const float* __restrict__ Wo,
    unsigned int* __restrict__ mask, ushort_t* __restrict__ hb,
    ushort_t* __restrict__ Wt, ushort_t* __restrict__ Wot) {
    const int bid = blockIdx.x;
    const int t = threadIdx.x;
    if (bid < 128) {
        uint4 z = {0u, 0u, 0u, 0u};
        ((uint4*)mask)[bid * 256 + t] = z;        // 512 KB
    } else if (bid < 1152) {
        int chunk = (bid - 128) * 256 + t;        // 262144 chunks of 8 floats
        float4 a = *(const float4*)(h + (size_t)chunk * 8);
        float4 b = *(const float4*)(h + (size_t)chunk * 8 + 4);
        ushort_t o[8] = {f2bf(a.x), f2bf(a.y), f2bf(a.z), f2bf(a.w),
                         f2bf(b.x), f2bf(b.y), f2bf(b.z), f2bf(b.w)};
        *(uint4*)(hb + (size_t)chunk * 8) = *(const uint4*)o;
    } else {
        int tg = (bid - 1152) * 256 + t;          // 262144 = 1024 rows x 256 cols
        int n = tg >> 8, k = tg & 255;
        if (n < 768) {
            const float* W = (n < 256) ? Wq : (n < 512) ? Wk : Wv;
            Wt[(size_t)n * 256 + k] = f2bf(W[(size_t)k * 256 + (n & 255)]);
        } else {
            int nn = n - 768;
            Wot[(size_t)nn * 256 + k] = f2bf(Wo[(size_t)k * 256 + nn]);
        }
    }
}

// ---------------- mask build: row-major bitmask mask[b*512+r][16 words] ----------------
__global__ void mask_build(const int* __restrict__ src, const int* __restrict__ dst,
                           unsigned int* __restrict__ mask) {
    int t = blockIdx.x * 256 + threadIdx.x;
    if (t < EE) {
        int s = src[t], d = dst[t];
        int b = s / NN, r = s % NN, c = d % NN;
        atomicOr(&mask[((size_t)(b * NN + r)) * 16 + (c >> 5)], 1u << (c & 31));
    }
    if (t < MM) {
        atomicOr(&mask[(size_t)t * 16 + ((t & 511) >> 5)], 1u << (t & 31));
    }
}

// ---------------- 128x128 MFMA GEMM, global_load_lds + XOR-swizzled LDS ----------------
// LDS linear [row][64] bf16 (128B rows); swizzle: 16B-slot ^= (row&7), applied on
// BOTH global source (stage) and ds_read (frags) -- rule 21.
__global__ __launch_bounds__(256) void gemm_qkv(
    const ushort_t* __restrict__ A, const ushort_t* __restrict__ Bt,
    const float* __restrict__ b0, const float* __restrict__ b1, const float* __restrict__ b2,
    ushort_t* __restrict__ qb, ushort_t* __restrict__ kb, ushort_t* __restrict__ vb) {
    __shared__ ushort_t As[128 * 64];
    __shared__ ushort_t Bs[128 * 64];
    const int t = threadIdx.x;
    const int m0 = blockIdx.x * 128, n0 = blockIdx.y * 128;
    const int wid = t >> 6, lane = t & 63, g = lane >> 4, c = lane & 15;
    const int wr = wid >> 1, wc = wid & 1;
    const int c7 = c & 7;

    f32x4 acc[4][4];
    #pragma unroll
    for (int mi = 0; mi < 4; ++mi)
        #pragma unroll
        for (int nj = 0; nj < 4; ++nj) acc[mi][nj] = (f32x4){0.f, 0.f, 0.f, 0.f};

    #define STAGE_QKV(kt) { \
        const int k0s = (kt) * 64; \
        _Pragma("unroll") \
        for (int i = 0; i < 4; ++i) { \
            int p = i * 256 + t; \
            int row = p >> 3, ss = (p & 7) ^ (row & 7); \
            int ldoff = (i * 256 + wid * 64) * 8; \
            gload16(A  + (size_t)(m0 + row) * 256 + k0s + ss * 8, &As[ldoff]); \
            gload16(Bt + (size_t)(n0 + row) * 256 + k0s + ss * 8, &Bs[ldoff]); \
        } \
    }

    STAGE_QKV(0);
    __syncthreads();                      // compiler drains vmcnt before barrier
    for (int kt = 0; kt < 4; ++kt) {
        #pragma unroll
        for (int kk = 0; kk < 2; ++kk) {
            bf16x8 av[4], bv4[4];
            #pragma unroll
            for (int mi = 0; mi < 4; ++mi) {
                int row = wr * 64 + mi * 16 + c;
                av[mi] = *(const bf16x8*)&As[row * 64 + (((kk * 4 + g) ^ c7) << 3)];
            }
            #pragma unroll
            for (int nj = 0; nj < 4; ++nj) {
                int row = wc * 64 + nj * 16 + c;
                bv4[nj] = *(const bf16x8*)&Bs[row * 64 + (((kk * 4 + g) ^ c7) << 3)];
            }
            #pragma unroll
            for (int mi = 0; mi < 4; ++mi)
                #pragma unroll
                for (int nj = 0; nj < 4; ++nj)
                    acc[mi][nj] = __builtin_amdgcn_mfma_f32_16x16x32_bf16(av[mi], bv4[nj], acc[mi][nj], 0, 0, 0);
        }
        if (kt < 3) {
            __syncthreads();              // all waves done reading
            STAGE_QKV(kt + 1);
            __syncthreads();              // staged + drained
        }
    }

    #pragma unroll
    for (int mi = 0; mi < 4; ++mi) {
        #pragma unroll
        for (int nj = 0; nj < 4; ++nj) {
            const f32x4 av = acc[mi][nj];
            const int m_base = m0 + wr * 64 + mi * 16 + 4 * g;
            const int n_base = n0 + wc * 64 + nj * 16;
            const int z = n_base >> 8, nn = n_base & 255;
            const int hh = nn >> 5, hd = (nn & 31) + c;
            const float* bp = (z == 0) ? b0 : (z == 1) ? b1 : b2;
            const float bias = bp[nn + c];
            const int b = m_base >> 9, nrow = m_base & 511;
            ushort_t* dst = (z == 0) ? qb : (z == 1) ? kb : vb;
            #pragma unroll
            for (int r = 0; r < 4; ++r)
                dst[(((size_t)(b * 8 + hh)) * 512 + nrow + r) * 32 + hd] = f2bf(av[r] + bias);
        }
    }
}

// ---------------- 64x64 MFMA GEMM (out-proj), same gload_lds + swizzle ----------------
__global__ __launch_bounds__(256) void gemm_out(
    const ushort_t* __restrict__ A, const ushort_t* __restrict__ Bt,
    const float* __restrict__ b0, float* __restrict__ fout) {
    __shared__ ushort_t As[64 * 64];
    __shared__ ushort_t Bs[64 * 64];
    const int t = threadIdx.x;
    const int m0 = blockIdx.x * 64, n0 = blockIdx.y * 64;
    const int wid = t >> 6, lane = t & 63, g = lane >> 4, c = lane & 15;
    const int wr = wid >> 1, wc = wid & 1;
    const int c7 = c & 7;

    f32x4 acc00 = {0.f,0.f,0.f,0.f}, acc01 = acc00, acc10 = acc00, acc11 = acc00;

    #define STAGE_OUT(kt) { \
        const int k0s = (kt) * 64; \
        _Pragma("unroll") \
        for (int i = 0; i < 2; ++i) { \
            int p = i * 256 + t; \
            int row = p >> 3, ss = (p & 7) ^ (row & 7); \
            int ldoff = (i * 256 + wid * 64) * 8; \
            gload16(A  + (size_t)(m0 + row) * 256 + k0s + ss * 8, &As[ldoff]); \
            gload16(Bt + (size_t)(n0 + row) * 256 + k0s + ss * 8, &Bs[ldoff]); \
        } \
    }

    STAGE_OUT(0);
    __syncthreads();
    for (int kt = 0; kt < 4; ++kt) {
        #pragma unroll
        for (int kk = 0; kk < 2; ++kk) {
            int sw = ((kk * 4 + g) ^ c7) << 3;
            bf16x8 a0 = *(const bf16x8*)&As[(wr * 32 + c) * 64 + sw];
            bf16x8 a1 = *(const bf16x8*)&As[(wr * 32 + 16 + c) * 64 + sw];
            bf16x8 bb0 = *(const bf16x8*)&Bs[(wc * 32 + c) * 64 + sw];
            bf16x8 bb1 = *(const bf16x8*)&Bs[(wc * 32 + 16 + c) * 64 + sw];
            acc00 = __builtin_amdgcn_mfma_f32_16x16x32_bf16(a0, bb0, acc00, 0, 0, 0);
            acc01 = __builtin_amdgcn_mfma_f32_16x16x32_bf16(a0, bb1, acc01, 0, 0, 0);
            acc10 = __builtin_amdgcn_mfma_f32_16x16x32_bf16(a1, bb0, acc10, 0, 0, 0);
            acc11 = __builtin_amdgcn_mfma_f32_16x16x32_bf16(a1, bb1, acc11, 0, 0, 0);
        }
        if (kt < 3) {
            __syncthreads();
            STAGE_OUT(kt + 1);
            __syncthreads();
        }
    }

    #pragma unroll
    for (int mi = 0; mi < 2; ++mi) {
        #pragma unroll
        for (int nj = 0; nj < 2; ++nj) {
            const f32x4 av = (mi == 0) ? (nj == 0 ? acc00 : acc01) : (nj == 0 ? acc10 : acc11);
            const int m_base = m0 + wr * 32 + mi * 16 + 4 * g;
            const int n_base = n0 + wc * 32 + nj * 16;
            const float bias = b0[n_base + c];
            #pragma unroll
            for (int r = 0; r < 4; ++r)
                fout[(size_t)(m_base + r) * 256 + n_base + c] = av[r] + bias;
        }
    }
}

// ---------------- sparse attention v3: XCD-graph-locality swizzle (validated) ----------------
__global__ __launch_bounds__(256) void attn_sparse3(
    const ushort_t* __restrict__ qb, const ushort_t* __restrict__ kb,
    const ushort_t* __restrict__ vb, const unsigned int* __restrict__ mask,
    ushort_t* __restrict__ attnb) {
    __shared__ ushort_t colsS[4][64];
    const int wid = threadIdx.x >> 6, lane = threadIdx.x & 63;
    const int xcd = blockIdx.x & 7, j = blockIdx.x >> 3;        // 2048 blocks
    const int b = xcd * 2 + (j >> 7);                           // graph
    const int q = (j & 127) * 4 + wid;
    const int row = b * 512 + q;
    const int e2 = lane >> 4, h = (lane >> 1) & 7, half = lane & 1;
    const float SCALE = 0.17677669529663687f;  // 1/sqrt(32)

    unsigned int word = (lane < 16) ? mask[(size_t)row * 16 + lane] : 0u;
    int pc = __popc(word);
    int pre = pc;
    #pragma unroll
    for (int o = 1; o < 16; o <<= 1) {
        int v = __shfl_up(pre, o);
        if ((lane & 15) >= o) pre += v;
    }
    int off = pre - pc;
    while (word) {
        int bit = __ffs(word) - 1;
        word &= word - 1;
        if (off < 64) colsS[wid][off] = (ushort_t)(lane * 32 + bit);
        ++off;
    }
    int cnt = __shfl(pre, 15);
    cnt = cnt < 64 ? cnt : 64;

    const size_t hb_base = ((size_t)(b * 8 + h)) * 512;
    const int d0 = half * 16;
    float qf[16];
    ld16bf(qb + (hb_base + q) * 32 + d0, qf);

    float acc[16];
    #pragma unroll
    for (int d = 0; d < 16; ++d) acc[d] = 0.f;
    float l = 0.f;

    #pragma unroll 2
    for (int e = 0; e < cnt; e += 4) {
        int slot = e + e2;
        int col = colsS[wid][slot < cnt ? slot : 0];
        const ushort_t* kp = kb + (hb_base + col) * 32 + d0;
        const ushort_t* vp = vb + (hb_base + col) * 32 + d0;
        float kf[16], vf[16];
        ld16bf(kp, kf);
        ld16bf(vp, vf);
        float s0 = 0.f, s1 = 0.f;
        #pragma unroll
        for (int d = 0; d < 8; ++d) {
            s0 = fmaf(qf[d], kf[d], s0);
            s1 = fmaf(qf[8 + d], kf[8 + d], s1);
        }
        float s = s0 + s1;
        s += __shfl_xor(s, 1);
        float p = (slot < cnt) ? __expf(fmaf(s, SCALE, -16.0f)) : 0.f;
        l += p;
        #pragma unroll
        for (int d = 0; d < 16; ++d) acc[d] = fmaf(p, vf[d], acc[d]);
    }

    #pragma unroll
    for (int d = 0; d < 16; ++d) {
        acc[d] += __shfl_xor(acc[d], 16);
        acc[d] += __shfl_xor(acc[d], 32);
    }
    l += __shfl_xor(l, 16);
    l += __shfl_xor(l, 32);

    if (e2 == 0) {
        float rl = 1.0f / l;
        ushort_t o[16];
        #pragma unroll
        for (int d = 0; d < 16; ++d) o[d] = f2bf(acc[d] * rl);
        ushort_t* op = attnb + (size_t)row * 256 + h * 32 + d0;
        *(uint4*)op       = *(const uint4*)o;
        *(uint4*)(op + 8) = *(const uint4*)(o + 8);
    }
}

extern "C" void kernel_launch(void* const* d_in, const int* in_sizes, int n_in,
                              void* d_out, int out_size, void* d_ws, size_t ws_size,
                              hipStream_t stream) {
    const float* hin = (const float*)d_in[0];
    const int* src   = (const int*)d_in[1];
    const int* dst   = (const int*)d_in[2];
    const float* Wq  = (const float*)d_in[3];
    const float* bq  = (const float*)d_in[4];
    const float* Wk  = (const float*)d_in[5];
    const float* bk  = (const float*)d_in[6];
    const float* Wv  = (const float*)d_in[7];
    const float* bv  = (const float*)d_in[8];
    const float* Wo  = (const float*)d_in[9];
    const float* bo  = (const float*)d_in[10];

    char* ws = (char*)d_ws;
    unsigned int* mask = (unsigned int*)ws;                      // 512 KB
    ushort_t* hb    = (ushort_t*)(ws + 2129920);                 // 4 MB
    ushort_t* qb    = (ushort_t*)(ws + 6324224);                 // 4 MB
    ushort_t* kb    = (ushort_t*)(ws + 10518528);                // 4 MB
    ushort_t* vb    = (ushort_t*)(ws + 14712832);                // 4 MB
    ushort_t* attnb = (ushort_t*)(ws + 18907136);                // 4 MB
    ushort_t* Wt    = (ushort_t*)(ws + 23101440);                // 384 KB
    ushort_t* Wot   = (ushort_t*)(ws + 23494656);                // 128 KB
    float* out = (float*)d_out;

    prep<<<2176, 256, 0, stream>>>(hin, Wq, Wk, Wv, Wo, mask, hb, Wt, Wot);
    mask_build<<<(EE + 255) / 256, 256, 0, stream>>>(src, dst, mask);
    gemm_qkv<<<dim3(MM / 128, 768 / 128), 256, 0, stream>>>(hb, Wt, bq, bk, bv, qb, kb, vb);
    attn_sparse3<<<MM / 4, 256, 0, stream>>>(qb, kb, vb, mask, attnb);
    gemm_out<<<dim3(MM / 64, 256 / 64), 256, 0, stream>>>(attnb, Wot, bo, out);
}